// Round 1
// baseline (491.738 us; speedup 1.0000x reference)
//
#include <hip/hip_runtime.h>
#include <hip/hip_bf16.h>
#include <math.h>

#define B_   8
#define S_   4096
#define FIN  256
#define C_   256
#define G_   8
#define D_   32
#define K_   31
#define PAD_ 15
#define FOUT 88

// ---------------- Kernel 1: fused QKV projection GEMM ----------------
// M = B*S = 32768, N = 256 per weight (3 weights), K = 256. fp32, 64x64 tile,
// BK=16, 4x4 per thread (16x16 thread grid).
__global__ __launch_bounds__(256) void qkv_gemm(
    const float* __restrict__ spec,
    const float* __restrict__ Wq, const float* __restrict__ Wk, const float* __restrict__ Wv,
    float* __restrict__ Q, float* __restrict__ Kb, float* __restrict__ Vb)
{
    __shared__ float As[16][64];   // As[kk][m]  (transposed A tile)
    __shared__ float Bs[16][64];   // Bs[kk][n]

    const int nt = blockIdx.x;     // 0..11  (which 64-col tile of the 768-wide output)
    const int mt = blockIdx.y;     // 0..511
    const int w  = nt >> 2;        // 0=Q, 1=K, 2=V
    const float* __restrict__ W   = (w == 0) ? Wq : (w == 1) ? Wk : Wv;
    float* __restrict__ Out       = (w == 0) ? Q  : (w == 1) ? Kb : Vb;
    const int n0 = (nt & 3) * 64;
    const int m0 = mt * 64;

    const int t  = threadIdx.x;
    const int tx = t & 15;         // N-dir
    const int ty = t >> 4;         // M-dir
    // A-tile load indices: 64 rows x 16 k, float4 per thread
    const int lr  = t >> 2;        // row 0..63
    const int lk  = (t & 3) * 4;   // k offset 0,4,8,12
    // B-tile load indices: 16 k-rows x 64 cols
    const int lbr = t >> 4;        // k-row 0..15
    const int lbc = (t & 15) * 4;  // col

    float acc[4][4] = {};

    for (int k0 = 0; k0 < 256; k0 += 16) {
        float4 a = *(const float4*)&spec[(size_t)(m0 + lr) * 256 + k0 + lk];
        As[lk + 0][lr] = a.x;
        As[lk + 1][lr] = a.y;
        As[lk + 2][lr] = a.z;
        As[lk + 3][lr] = a.w;
        *(float4*)&Bs[lbr][lbc] = *(const float4*)&W[(size_t)(k0 + lbr) * 256 + n0 + lbc];
        __syncthreads();
#pragma unroll
        for (int kk = 0; kk < 16; ++kk) {
            float4 a4 = *(const float4*)&As[kk][ty * 4];
            float4 b4 = *(const float4*)&Bs[kk][tx * 4];
            acc[0][0] += a4.x * b4.x; acc[0][1] += a4.x * b4.y; acc[0][2] += a4.x * b4.z; acc[0][3] += a4.x * b4.w;
            acc[1][0] += a4.y * b4.x; acc[1][1] += a4.y * b4.y; acc[1][2] += a4.y * b4.z; acc[1][3] += a4.y * b4.w;
            acc[2][0] += a4.z * b4.x; acc[2][1] += a4.z * b4.y; acc[2][2] += a4.z * b4.z; acc[2][3] += a4.z * b4.w;
            acc[3][0] += a4.w * b4.x; acc[3][1] += a4.w * b4.y; acc[3][2] += a4.w * b4.z; acc[3][3] += a4.w * b4.w;
        }
        __syncthreads();
    }
#pragma unroll
    for (int i = 0; i < 4; ++i) {
        float4 o = make_float4(acc[i][0], acc[i][1], acc[i][2], acc[i][3]);
        *(float4*)&Out[(size_t)(m0 + ty * 4 + i) * 256 + n0 + tx * 4] = o;
    }
}

// ---------------- Kernel 2: fused windowed attention + linear + sigmoid ----
// One block = 32 consecutive s rows x 8 heads = 256 threads (1 thread per (s,g)).
// smem reused: phase A = rel staged as relS[k*288 + g*36 + d] (conflict-free
// float4 reads across g); phase B = outS[sl*264 + g*33 + d] transpose buffer.
__global__ __launch_bounds__(256) void attn_fused(
    const float* __restrict__ Q, const float* __restrict__ Kb, const float* __restrict__ Vb,
    const float* __restrict__ rel, const float* __restrict__ Wl, const float* __restrict__ bl,
    float* __restrict__ frame, float* __restrict__ attn)
{
    __shared__ float smem[31 * 288];    // 8928 floats = 35.7 KB (>= 32*264)

    const int blk = blockIdx.x;         // 0..1023
    const int b   = blk >> 7;
    const int s0  = (blk & 127) * 32;
    const int t   = threadIdx.x;
    const int g   = t & 7;
    const int sl  = t >> 3;
    const int s   = s0 + sl;
    const size_t rowb = (size_t)b * S_;
    const size_t row  = rowb + s;

    // ---- stage rel [C,K] -> relS[k*288 + (c>>5)*36 + (c&31)] ----
    for (int i = t; i < C_ * K_; i += 256) {
        int c = i / K_;
        int k = i - c * K_;
        smem[k * 288 + (c >> 5) * 36 + (c & 31)] = rel[i];
    }
    __syncthreads();

    // ---- load q (32 floats, this thread's head slice) ----
    float q[32];
    {
        const float4* qp = (const float4*)&Q[row * 256 + (size_t)g * 32];
#pragma unroll
        for (int j = 0; j < 8; ++j) {
            float4 v = qp[j];
            q[4 * j + 0] = v.x; q[4 * j + 1] = v.y; q[4 * j + 2] = v.z; q[4 * j + 3] = v.w;
        }
    }

    // ---- energy: e[k] = q . (K[s-15+k] + rel[:,k]); out-of-range K row = 0 ----
    float e[31];
#pragma unroll
    for (int k = 0; k < K_; ++k) {
        int s2 = s - PAD_ + k;
        const float4* rp = (const float4*)&smem[k * 288 + g * 36];
        float acc = 0.f;
        if ((unsigned)s2 < (unsigned)S_) {
            const float4* kp = (const float4*)&Kb[(rowb + (size_t)s2) * 256 + (size_t)g * 32];
#pragma unroll
            for (int j = 0; j < 8; ++j) {
                float4 kv = kp[j];
                float4 rv = rp[j];
                acc += q[4 * j + 0] * (kv.x + rv.x) + q[4 * j + 1] * (kv.y + rv.y)
                     + q[4 * j + 2] * (kv.z + rv.z) + q[4 * j + 3] * (kv.w + rv.w);
            }
        } else {
#pragma unroll
            for (int j = 0; j < 8; ++j) {
                float4 rv = rp[j];
                acc += q[4 * j + 0] * rv.x + q[4 * j + 1] * rv.y
                     + q[4 * j + 2] * rv.z + q[4 * j + 3] * rv.w;
            }
        }
        e[k] = acc;
    }

    // ---- softmax over K=31 (in registers) ----
    float mx = e[0];
#pragma unroll
    for (int k = 1; k < K_; ++k) mx = fmaxf(mx, e[k]);
    float sum = 0.f;
#pragma unroll
    for (int k = 0; k < K_; ++k) { e[k] = __expf(e[k] - mx); sum += e[k]; }
    float inv = 1.f / sum;
#pragma unroll
    for (int k = 0; k < K_; ++k) e[k] *= inv;

    // ---- write attn output [B,S,G,K] ----
    {
        float* ap = &attn[row * (size_t)(G_ * K_) + (size_t)g * K_];
#pragma unroll
        for (int k = 0; k < K_; ++k) ap[k] = e[k];
    }

    // ---- PV: o[d] = sum_k attn_k * V[s-15+k, g*32+d] ----
    float o[32] = {};
#pragma unroll
    for (int k = 0; k < K_; ++k) {
        int s2 = s - PAD_ + k;
        if ((unsigned)s2 < (unsigned)S_) {
            float a = e[k];
            const float4* vp = (const float4*)&Vb[(rowb + (size_t)s2) * 256 + (size_t)g * 32];
#pragma unroll
            for (int j = 0; j < 8; ++j) {
                float4 vv = vp[j];
                o[4 * j + 0] += a * vv.x; o[4 * j + 1] += a * vv.y;
                o[4 * j + 2] += a * vv.z; o[4 * j + 3] += a * vv.w;
            }
        }
    }

    __syncthreads();   // all relS reads done before smem reuse

    // ---- transpose to outS[sl*264 + g*33 + d] (2-way max on banks: free) ----
#pragma unroll
    for (int d = 0; d < 32; ++d)
        smem[sl * 264 + g * 33 + d] = o[d];
    __syncthreads();

    // ---- final linear [256->88] + bias + sigmoid ----
    const int r  = t >> 3;       // row 0..31
    const int fg = t & 7;        // f = fg + 8*j, j=0..10
    float acc2[11] = {};
    for (int c = 0; c < 256; ++c) {
        float ov = smem[r * 264 + (c >> 5) * 33 + (c & 31)];
        const float* wp = &Wl[(size_t)c * FOUT + fg];
#pragma unroll
        for (int j = 0; j < 11; ++j) acc2[j] += ov * wp[8 * j];
    }
    const size_t rrow = rowb + s0 + r;
#pragma unroll
    for (int j = 0; j < 11; ++j) {
        int f = fg + 8 * j;
        float x = acc2[j] + bl[f];
        frame[rrow * FOUT + f] = 1.f / (1.f + __expf(-x));
    }
}

extern "C" void kernel_launch(void* const* d_in, const int* in_sizes, int n_in,
                              void* d_out, int out_size, void* d_ws, size_t ws_size,
                              hipStream_t stream) {
    (void)in_sizes; (void)n_in; (void)out_size; (void)ws_size;
    const float* spec = (const float*)d_in[0];
    const float* Wq   = (const float*)d_in[1];
    const float* Wk   = (const float*)d_in[2];
    const float* Wv   = (const float*)d_in[3];
    const float* rel  = (const float*)d_in[4];
    const float* Wl   = (const float*)d_in[5];
    const float* bl   = (const float*)d_in[6];

    float* frame = (float*)d_out;                              // [B,S,88]
    float* attn  = frame + (size_t)B_ * S_ * FOUT;             // [B,S,G,K]

    float* Q  = (float*)d_ws;                                  // [B*S, 256] each
    float* Kb = Q  + (size_t)B_ * S_ * C_;
    float* Vb = Kb + (size_t)B_ * S_ * C_;

    qkv_gemm<<<dim3(12, 512), 256, 0, stream>>>(spec, Wq, Wk, Wv, Q, Kb, Vb);
    attn_fused<<<dim3(1024), 256, 0, stream>>>(Q, Kb, Vb, rel, Wl, bl, frame, attn);
}